// Round 6
// baseline (464.406 us; speedup 1.0000x reference)
//
#include <hip/hip_runtime.h>
#include <hip/hip_cooperative_groups.h>
#include <math.h>

namespace cg = cooperative_groups;

#define BB 8
#define TT 4095
#define DD 1024
#define NN 7
#define GG 585           // TT / NN
#define BN (BB * NN)     // 56
#define GSPLIT 16
#define GCHUNK 37        // ceil(585/16)
#define GD 2             // output columns per gemv block-unit
#define NROWS (BB * TT)  // 32760

typedef float nfloat4 __attribute__((ext_vector_type(4)));

// ---------------------------------------------------------------------------
// gemv unit: C[bn][d0:d0+GD] for all 56 rows.  blk in [0, DD/GD).
// Wave w owns rows [14w, 14w+14); lanes span full K (4 x float4 each).
// ---------------------------------------------------------------------------
__device__ __forceinline__ void gemv_body(
    const float* __restrict__ A, const float* __restrict__ Wm,
    float* __restrict__ C, int blk, int t) {
    int d0 = blk * GD;
    int wave = t >> 6, lane = t & 63;

    float4 wv[GD][4];
    #pragma unroll
    for (int dd = 0; dd < GD; ++dd) {
        const float4* wp = (const float4*)(Wm + (size_t)(d0 + dd) * DD);
        #pragma unroll
        for (int kk = 0; kk < 4; ++kk) wv[dd][kk] = wp[lane + 64 * kk];
    }

    const float4* ap = (const float4*)A + (size_t)(wave * 14) * (DD / 4);
    float acc[14][GD];
    #pragma unroll
    for (int i = 0; i < 14; ++i) {
        const float4* ar = ap + (size_t)i * (DD / 4);
        float4 a0 = ar[lane];
        float4 a1 = ar[lane + 64];
        float4 a2 = ar[lane + 128];
        float4 a3 = ar[lane + 192];
        #pragma unroll
        for (int dd = 0; dd < GD; ++dd) {
            float v = a0.x * wv[dd][0].x + a0.y * wv[dd][0].y +
                      a0.z * wv[dd][0].z + a0.w * wv[dd][0].w;
            v += a1.x * wv[dd][1].x + a1.y * wv[dd][1].y +
                 a1.z * wv[dd][1].z + a1.w * wv[dd][1].w;
            v += a2.x * wv[dd][2].x + a2.y * wv[dd][2].y +
                 a2.z * wv[dd][2].z + a2.w * wv[dd][2].w;
            v += a3.x * wv[dd][3].x + a3.y * wv[dd][3].y +
                 a3.z * wv[dd][3].z + a3.w * wv[dd][3].w;
            acc[i][dd] = v;
        }
    }

    #pragma unroll
    for (int i = 0; i < 14; ++i) {
        #pragma unroll
        for (int dd = 0; dd < GD; ++dd) {
            float v = acc[i][dd];
            v += __shfl_xor(v, 1, 64);
            v += __shfl_xor(v, 2, 64);
            v += __shfl_xor(v, 4, 64);
            v += __shfl_xor(v, 8, 64);
            v += __shfl_xor(v, 16, 64);
            v += __shfl_xor(v, 32, 64);
            if (lane == 0) C[(size_t)(wave * 14 + i) * DD + d0 + dd] = v;
        }
    }
}

// ---------------------------------------------------------------------------
// Stage bodies shared by the fused and fallback paths.
// ---------------------------------------------------------------------------
__device__ __forceinline__ void mean_partial_body(
    const float* __restrict__ x, float* __restrict__ partial, int unit, int t) {
    int bn = unit >> 4;              // /GSPLIT
    int gs = unit & (GSPLIT - 1);
    int b = bn / NN, n = bn % NN;
    int g0 = gs * GCHUNK;
    int g1 = g0 + GCHUNK; if (g1 > GG) g1 = GG;
    const float4* xp = (const float4*)(x + (size_t)(b * TT + n) * DD) + t;
    float ax = 0.f, ay = 0.f, az = 0.f, aw = 0.f;
    #pragma unroll 4
    for (int g = g0; g < g1; ++g) {
        float4 v = xp[(size_t)g * NN * (DD / 4)];
        ax += v.x; ay += v.y; az += v.z; aw += v.w;
    }
    float4 r; r.x = ax; r.y = ay; r.z = az; r.w = aw;
    ((float4*)partial)[(size_t)(gs * BN + bn) * (DD / 4) + t] = r;
}

__device__ __forceinline__ void mean_reduce_body(
    const float* __restrict__ partial, float* __restrict__ nodes, int unit, int t) {
    int i = unit * 256 + t;
    const float4* p = (const float4*)partial;
    float4 a = p[i];
    #pragma unroll
    for (int gs = 1; gs < GSPLIT; ++gs) {
        float4 v = p[(size_t)gs * BN * (DD / 4) + i];
        a.x += v.x; a.y += v.y; a.z += v.z; a.w += v.w;
    }
    const float sc = 1.0f / (float)GG;
    a.x *= sc; a.y *= sc; a.z *= sc; a.w *= sc;
    ((float4*)nodes)[i] = a;
}

__device__ __forceinline__ void final_body(
    const float* __restrict__ x, const float* __restrict__ on,
    float* __restrict__ out, int row, int t) {
    int b = row / TT;
    int tt = row - b * TT;
    int n = tt % NN;
    size_t row4 = (size_t)row * (DD / 4) + t;
    size_t on4 = (size_t)(b * NN + n) * (DD / 4) + t;
    float4 xv = ((const float4*)x)[row4];
    float4 ov = ((const float4*)on)[on4];
    nfloat4 r;
    r.x = xv.x + ov.x; r.y = xv.y + ov.y;
    r.z = xv.z + ov.z; r.w = xv.w + ov.w;
    __builtin_nontemporal_store(r, (nfloat4*)out + row4);
}

// attn for one batch b; uses provided LDS buffers. block = 256.
__device__ __forceinline__ void attn_body(
    const float* __restrict__ h, const float* __restrict__ a_w,
    float* __restrict__ s, int b, int t,
    float (*hl)[DD], float (*f)[NN], float (*alpha)[NN]) {
    const float4* hp = (const float4*)(h + (size_t)b * NN * DD);
    float4* hl4 = (float4*)hl;
    for (int i = t; i < NN * (DD / 4); i += 256) hl4[i] = hp[i];
    __syncthreads();

    int wave = t >> 6, lane = t & 63;
    for (int task = wave; task < 2 * NN; task += 4) {
        int n = task % NN, sel = task / NN;
        const float* av = a_w + sel * DD;
        float sum = 0.f;
        for (int k = lane; k < DD; k += 64) sum += hl[n][k] * av[k];
        sum += __shfl_xor(sum, 1, 64);
        sum += __shfl_xor(sum, 2, 64);
        sum += __shfl_xor(sum, 4, 64);
        sum += __shfl_xor(sum, 8, 64);
        sum += __shfl_xor(sum, 16, 64);
        sum += __shfl_xor(sum, 32, 64);
        if (lane == 0) f[sel][n] = sum;
    }
    __syncthreads();

    if (t == 0) {
        const unsigned msk[NN] = {0x7Eu, 0x45u, 0x0Bu, 0x15u, 0x29u, 0x51u, 0x23u};
        #pragma unroll
        for (int i = 0; i < NN; ++i) {
            float m = -1e30f;
            #pragma unroll
            for (int j = 0; j < NN; ++j)
                if ((msk[i] >> j) & 1u) { float e = f[0][i] + f[1][j]; m = fmaxf(m, e); }
            float ssum = 0.f; float ex[NN];
            #pragma unroll
            for (int j = 0; j < NN; ++j) {
                ex[j] = ((msk[i] >> j) & 1u) ? expf(f[0][i] + f[1][j] - m) : 0.f;
                ssum += ex[j];
            }
            float inv = 1.0f / ssum;
            #pragma unroll
            for (int j = 0; j < NN; ++j) alpha[i][j] = ex[j] * inv;
        }
    }
    __syncthreads();

    float4* sp = (float4*)(s + (size_t)b * NN * DD);
    #pragma unroll
    for (int i = 0; i < NN; ++i) {
        float ax = 0.f, ay = 0.f, az = 0.f, aw = 0.f;
        #pragma unroll
        for (int j = 0; j < NN; ++j) {
            float a = alpha[i][j];
            float4 hv = hl4[j * (DD / 4) + t];
            ax += a * hv.x; ay += a * hv.y; az += a * hv.z; aw += a * hv.w;
        }
        float4 r; r.x = ax; r.y = ay; r.z = az; r.w = aw;
        sp[i * (DD / 4) + t] = r;
    }
}

// ---------------------------------------------------------------------------
// Fused cooperative kernel. Grid size passed as arg; all stages grid-stride.
// ---------------------------------------------------------------------------
__global__ __launch_bounds__(256, 4) void k_fused(
    const float* __restrict__ x, const float* __restrict__ W,
    const float* __restrict__ a_w, const float* __restrict__ out_W,
    float* __restrict__ out,
    float* __restrict__ partial, float* __restrict__ nodes,
    float* __restrict__ h, float* __restrict__ s, float* __restrict__ on,
    int nblk) {

    cg::grid_group grid = cg::this_grid();
    int bid = blockIdx.x;
    int t = threadIdx.x;

    __shared__ float hl[NN][DD];          // 28 KB (attn stage)
    __shared__ float f[2][NN];
    __shared__ float alpha[NN][NN];

    for (int u = bid; u < BN * GSPLIT; u += nblk) mean_partial_body(x, partial, u, t);
    grid.sync();

    for (int u = bid; u < BN; u += nblk) mean_reduce_body(partial, nodes, u, t);
    grid.sync();

    for (int u = bid; u < DD / GD; u += nblk) gemv_body(nodes, W, h, u, t);
    grid.sync();

    for (int u = bid; u < BB; u += nblk) attn_body(h, a_w, s, u, t, hl, f, alpha);
    grid.sync();

    for (int u = bid; u < DD / GD; u += nblk) gemv_body(s, out_W, on, u, t);
    grid.sync();

    for (int row = bid; row < NROWS; row += nblk) final_body(x, on, out, row, t);
}

// ---------------------------------------------------------------------------
// Fallback kernels (R4-equivalent path).
// ---------------------------------------------------------------------------
__global__ __launch_bounds__(256) void k_mean_partial(
    const float* __restrict__ x, float* __restrict__ partial) {
    mean_partial_body(x, partial, blockIdx.y * GSPLIT + blockIdx.x, threadIdx.x);
}

__global__ __launch_bounds__(256) void k_mean_reduce(
    const float* __restrict__ partial, float* __restrict__ nodes) {
    mean_reduce_body(partial, nodes, blockIdx.x, threadIdx.x);
}

__global__ __launch_bounds__(256) void k_gemv(
    const float* __restrict__ A, const float* __restrict__ Wm,
    float* __restrict__ Cout) {
    gemv_body(A, Wm, Cout, blockIdx.x, threadIdx.x);
}

__global__ __launch_bounds__(256) void k_attn(
    const float* __restrict__ h, const float* __restrict__ a_w,
    float* __restrict__ s) {
    __shared__ float hl[NN][DD];
    __shared__ float f[2][NN];
    __shared__ float alpha[NN][NN];
    attn_body(h, a_w, s, blockIdx.x, threadIdx.x, hl, f, alpha);
}

__global__ __launch_bounds__(256) void k_final(
    const float* __restrict__ x, const float* __restrict__ on,
    float* __restrict__ out) {
    final_body(x, on, out, blockIdx.y * TT + blockIdx.x, threadIdx.x);
}

// ---------------------------------------------------------------------------
extern "C" void kernel_launch(void* const* d_in, const int* in_sizes, int n_in,
                              void* d_out, int out_size, void* d_ws, size_t ws_size,
                              hipStream_t stream) {
    const float* x     = (const float*)d_in[0];
    const float* W     = (const float*)d_in[1];
    const float* a_w   = (const float*)d_in[2];
    const float* out_W = (const float*)d_in[3];
    float* out = (float*)d_out;
    float* ws  = (float*)d_ws;

    // ws layout (floats)
    float* partial = ws;                            // 16*56*1024 = 917504
    float* nodes   = ws + 917504;                   // 56*1024
    float* h       = ws + 917504 + 57344;           // 56*1024
    float* s       = ws + 917504 + 2 * 57344;       // 56*1024
    float* on      = ws + 917504 + 3 * 57344;       // 56*1024

    // Ask the runtime for the real cooperative capacity (host-only, capture-safe).
    int occ = 0;
    hipError_t oe = hipOccupancyMaxActiveBlocksPerMultiprocessor(&occ, k_fused, 256, 0);
    bool done = false;
    if (oe == hipSuccess && occ > 0) {
        int nblk = occ * 256;               // 256 CUs on MI355X
        if (nblk > 1024) nblk = 1024;
        void* args[] = {(void*)&x, (void*)&W, (void*)&a_w, (void*)&out_W,
                        (void*)&out, (void*)&partial, (void*)&nodes,
                        (void*)&h, (void*)&s, (void*)&on, (void*)&nblk};
        hipError_t le = hipLaunchCooperativeKernel((const void*)k_fused,
                                                   dim3(nblk), dim3(256),
                                                   args, 0, stream);
        if (le == hipSuccess) done = true;
    }

    if (!done) {
        // Fallback: proven 6-kernel path.
        k_mean_partial<<<dim3(GSPLIT, BN), 256, 0, stream>>>(x, partial);
        k_mean_reduce<<<dim3(BN), 256, 0, stream>>>(partial, nodes);
        k_gemv<<<dim3(DD / GD), 256, 0, stream>>>(nodes, W, h);
        k_attn<<<dim3(BB), 256, 0, stream>>>(h, a_w, s);
        k_gemv<<<dim3(DD / GD), 256, 0, stream>>>(s, out_W, on);
        k_final<<<dim3(TT, BB), 256, 0, stream>>>(x, on, out);
    }
}

// Round 7
// 146.621 us; speedup vs baseline: 3.1674x; 3.1674x over previous
//
#include <hip/hip_runtime.h>
#include <math.h>

#define BB 8
#define TT 4095
#define DD 1024
#define NN 7
#define GG 585           // TT / NN
#define BN (BB * NN)     // 56
#define GSPLIT 16
#define GCHUNK 37        // ceil(585/16)
#define GD 4             // gemv1: output columns per block
#define GD2 2            // gemv2+attn: output columns per block (VGPR budget)
#define NROWS (BB * TT)  // 32760
#define FBLK 4096        // k_final grid

typedef float nfloat4 __attribute__((ext_vector_type(4)));

// ---------------------------------------------------------------------------
// K1: partial group-mean, scaled, atomically accumulated into nodes.
// grid = (GSPLIT, BN), block = 256.  nodes must be zeroed beforehand.
// ---------------------------------------------------------------------------
__global__ __launch_bounds__(256) void k_mean_atomic(
    const float* __restrict__ x, float* __restrict__ nodes) {
    int gs = blockIdx.x;             // 0..15
    int bn = blockIdx.y;             // 0..55
    int b = bn / NN, n = bn % NN;
    int t = threadIdx.x;             // float4 index within row
    int g0 = gs * GCHUNK;
    int g1 = g0 + GCHUNK; if (g1 > GG) g1 = GG;

    const float4* xp = (const float4*)(x + (size_t)(b * TT + n) * DD) + t;
    float ax = 0.f, ay = 0.f, az = 0.f, aw = 0.f;
    #pragma unroll 4
    for (int g = g0; g < g1; ++g) {
        float4 v = xp[(size_t)g * NN * (DD / 4)];
        ax += v.x; ay += v.y; az += v.z; aw += v.w;
    }
    const float sc = 1.0f / (float)GG;
    float* np = nodes + (size_t)bn * DD + t * 4;
    atomicAdd(np + 0, ax * sc);
    atomicAdd(np + 1, ay * sc);
    atomicAdd(np + 2, az * sc);
    atomicAdd(np + 3, aw * sc);
}

// ---------------------------------------------------------------------------
// K2: h[bn][d] = sum_k nodes[bn][k] * W[d][k].  grid = DD/GD = 256, block 256.
// Wave w owns rows [14w,14w+14); lanes span full K (4 x float4 each).
// ---------------------------------------------------------------------------
__global__ __launch_bounds__(256) void k_gemv(
    const float* __restrict__ A, const float* __restrict__ Wm,
    float* __restrict__ Cout) {
    int d0 = blockIdx.x * GD;
    int t = threadIdx.x;
    int wave = t >> 6, lane = t & 63;

    float4 wv[GD][4];
    #pragma unroll
    for (int dd = 0; dd < GD; ++dd) {
        const float4* wp = (const float4*)(Wm + (size_t)(d0 + dd) * DD);
        #pragma unroll
        for (int kk = 0; kk < 4; ++kk) wv[dd][kk] = wp[lane + 64 * kk];
    }

    const float4* ap = (const float4*)A + (size_t)(wave * 14) * (DD / 4);
    float acc[14][GD];
    #pragma unroll
    for (int i = 0; i < 14; ++i) {
        const float4* ar = ap + (size_t)i * (DD / 4);
        float4 a0 = ar[lane];
        float4 a1 = ar[lane + 64];
        float4 a2 = ar[lane + 128];
        float4 a3 = ar[lane + 192];
        #pragma unroll
        for (int dd = 0; dd < GD; ++dd) {
            float v = a0.x * wv[dd][0].x + a0.y * wv[dd][0].y +
                      a0.z * wv[dd][0].z + a0.w * wv[dd][0].w;
            v += a1.x * wv[dd][1].x + a1.y * wv[dd][1].y +
                 a1.z * wv[dd][1].z + a1.w * wv[dd][1].w;
            v += a2.x * wv[dd][2].x + a2.y * wv[dd][2].y +
                 a2.z * wv[dd][2].z + a2.w * wv[dd][2].w;
            v += a3.x * wv[dd][3].x + a3.y * wv[dd][3].y +
                 a3.z * wv[dd][3].z + a3.w * wv[dd][3].w;
            acc[i][dd] = v;
        }
    }

    #pragma unroll
    for (int i = 0; i < 14; ++i) {
        #pragma unroll
        for (int dd = 0; dd < GD; ++dd) {
            float v = acc[i][dd];
            v += __shfl_xor(v, 1, 64);
            v += __shfl_xor(v, 2, 64);
            v += __shfl_xor(v, 4, 64);
            v += __shfl_xor(v, 8, 64);
            v += __shfl_xor(v, 16, 64);
            v += __shfl_xor(v, 32, 64);
            if (lane == 0) Cout[(size_t)(wave * 14 + i) * DD + d0 + dd] = v;
        }
    }
}

// ---------------------------------------------------------------------------
// K3: fused attention + gemv2.  on[bn][d] = (alpha_b @ h_b)[i] @ out_W[d]^T.
// grid = DD/GD2 = 512, block 256.
// Prologue: block cooperatively computes f[2][56] (h@a1, h@a2) into LDS.
// Main: wave w owns rows [14w,14w+14) = batches {2w, 2w+1}; computes alpha
// in registers and forms A-values on the fly: s[bn][k] = sum_j a_ij h[b][j][k].
// ---------------------------------------------------------------------------
__global__ __launch_bounds__(256) void k_attn_gemv(
    const float* __restrict__ h, const float* __restrict__ a_w,
    const float* __restrict__ Wm, float* __restrict__ Cout) {
    int d0 = blockIdx.x * GD2;
    int t = threadIdx.x;
    int wave = t >> 6, lane = t & 63;

    __shared__ float f[2][BN];

    // --- f[sel][bn] = h[bn][:] @ a_w[sel*DD ...] ---
    for (int task = wave; task < 2 * BN; task += 4) {
        int sel = task & 1;
        int bn = task >> 1;
        const float4* hv4 = (const float4*)(h + (size_t)bn * DD);
        const float4* av4 = (const float4*)(a_w + sel * DD);
        float sum = 0.f;
        #pragma unroll
        for (int c = 0; c < 4; ++c) {
            float4 a = hv4[lane + 64 * c];
            float4 w = av4[lane + 64 * c];
            sum += a.x * w.x + a.y * w.y + a.z * w.z + a.w * w.w;
        }
        sum += __shfl_xor(sum, 1, 64);
        sum += __shfl_xor(sum, 2, 64);
        sum += __shfl_xor(sum, 4, 64);
        sum += __shfl_xor(sum, 8, 64);
        sum += __shfl_xor(sum, 16, 64);
        sum += __shfl_xor(sum, 32, 64);
        if (lane == 0) f[sel][bn] = sum;
    }
    __syncthreads();

    float4 wv[GD2][4];
    #pragma unroll
    for (int dd = 0; dd < GD2; ++dd) {
        const float4* wp = (const float4*)(Wm + (size_t)(d0 + dd) * DD);
        #pragma unroll
        for (int kk = 0; kk < 4; ++kk) wv[dd][kk] = wp[lane + 64 * kk];
    }

    const unsigned msk[NN] = {0x7Eu, 0x45u, 0x0Bu, 0x15u, 0x29u, 0x51u, 0x23u};
    float acc[14][GD2];
    #pragma unroll
    for (int i = 0; i < 14; ++i)
        #pragma unroll
        for (int dd = 0; dd < GD2; ++dd) acc[i][dd] = 0.f;

    #pragma unroll
    for (int bb = 0; bb < 2; ++bb) {
        int b = wave * 2 + bb;

        // alpha[7][7] in registers (fully unrolled indexing)
        float alpha[NN][NN];
        #pragma unroll
        for (int i = 0; i < NN; ++i) {
            float f1 = f[0][b * NN + i];
            float m = -1e30f;
            #pragma unroll
            for (int j = 0; j < NN; ++j)
                if ((msk[i] >> j) & 1u) m = fmaxf(m, f1 + f[1][b * NN + j]);
            float ssum = 0.f;
            #pragma unroll
            for (int j = 0; j < NN; ++j) {
                float e = ((msk[i] >> j) & 1u) ? __expf(f1 + f[1][b * NN + j] - m) : 0.f;
                alpha[i][j] = e;
                ssum += e;
            }
            float inv = 1.0f / ssum;
            #pragma unroll
            for (int j = 0; j < NN; ++j) alpha[i][j] *= inv;
        }

        // gemv over 4 k-chunks, reusing h7 across the 7 rows of this batch
        #pragma unroll
        for (int c = 0; c < 4; ++c) {
            float4 h7[NN];
            #pragma unroll
            for (int j = 0; j < NN; ++j)
                h7[j] = ((const float4*)(h + (size_t)(b * NN + j) * DD))[lane + 64 * c];
            #pragma unroll
            for (int i = 0; i < NN; ++i) {
                float ax = 0.f, ay = 0.f, az = 0.f, aw = 0.f;
                #pragma unroll
                for (int j = 0; j < NN; ++j) {
                    float a = alpha[i][j];
                    ax += a * h7[j].x; ay += a * h7[j].y;
                    az += a * h7[j].z; aw += a * h7[j].w;
                }
                #pragma unroll
                for (int dd = 0; dd < GD2; ++dd) {
                    acc[bb * NN + i][dd] += ax * wv[dd][c].x + ay * wv[dd][c].y +
                                            az * wv[dd][c].z + aw * wv[dd][c].w;
                }
            }
        }
    }

    #pragma unroll
    for (int i = 0; i < 14; ++i) {
        #pragma unroll
        for (int dd = 0; dd < GD2; ++dd) {
            float v = acc[i][dd];
            v += __shfl_xor(v, 1, 64);
            v += __shfl_xor(v, 2, 64);
            v += __shfl_xor(v, 4, 64);
            v += __shfl_xor(v, 8, 64);
            v += __shfl_xor(v, 16, 64);
            v += __shfl_xor(v, 32, 64);
            if (lane == 0) Cout[(size_t)(wave * 14 + i) * DD + d0 + dd] = v;
        }
    }
}

// ---------------------------------------------------------------------------
// K4: out[b,t,d] = x[b,t,d] + on[b, t%7, d].  grid = FBLK, grid-stride rows.
// nt-store keeps out from evicting x in L3 (x 134 MB < 256 MB L3).
// ---------------------------------------------------------------------------
__global__ __launch_bounds__(256) void k_final(
    const float* __restrict__ x, const float* __restrict__ on,
    float* __restrict__ out) {
    int t = threadIdx.x;
    for (int row = blockIdx.x; row < NROWS; row += FBLK) {
        int b = row / TT;
        int tt = row - b * TT;
        int n = tt % NN;
        size_t row4 = (size_t)row * (DD / 4) + t;
        size_t on4 = (size_t)(b * NN + n) * (DD / 4) + t;
        float4 xv = ((const float4*)x)[row4];
        float4 ov = ((const float4*)on)[on4];
        nfloat4 r;
        r.x = xv.x + ov.x; r.y = xv.y + ov.y;
        r.z = xv.z + ov.z; r.w = xv.w + ov.w;
        __builtin_nontemporal_store(r, (nfloat4*)out + row4);
    }
}

// ---------------------------------------------------------------------------
extern "C" void kernel_launch(void* const* d_in, const int* in_sizes, int n_in,
                              void* d_out, int out_size, void* d_ws, size_t ws_size,
                              hipStream_t stream) {
    const float* x     = (const float*)d_in[0];
    const float* W     = (const float*)d_in[1];
    const float* a_w   = (const float*)d_in[2];
    const float* out_W = (const float*)d_in[3];
    float* out = (float*)d_out;
    float* ws  = (float*)d_ws;

    // ws layout (floats)
    float* nodes = ws;               // 56*1024
    float* h     = ws + 57344;       // 56*1024
    float* on    = ws + 2 * 57344;   // 56*1024

    hipMemsetAsync(nodes, 0, (size_t)BN * DD * sizeof(float), stream);
    k_mean_atomic<<<dim3(GSPLIT, BN), 256, 0, stream>>>(x, nodes);
    k_gemv<<<dim3(DD / GD), 256, 0, stream>>>(nodes, W, h);
    k_attn_gemv<<<dim3(DD / GD2), 256, 0, stream>>>(h, a_w, out_W, on);
    k_final<<<dim3(FBLK), 256, 0, stream>>>(x, on, out);
}

// Round 8
// 135.379 us; speedup vs baseline: 3.4304x; 1.0830x over previous
//
#include <hip/hip_runtime.h>
#include <math.h>

#define BB 8
#define TT 4095
#define DD 1024
#define NN 7
#define GG 585           // TT / NN
#define BN (BB * NN)     // 56
#define GSPLIT 16
#define GCHUNK 37        // ceil(585/16)
#define GD 4             // gemv1: output columns per block
#define GD2 2            // attn+gemv2: output columns per block

typedef float nfloat4 __attribute__((ext_vector_type(4)));

// ---------------------------------------------------------------------------
// K1: partial group-mean sums.  grid = (GSPLIT, BN), block = 256.  [R4 exact]
// ---------------------------------------------------------------------------
__global__ __launch_bounds__(256) void k_mean_partial(
    const float* __restrict__ x, float* __restrict__ partial) {
    int gs = blockIdx.x;             // 0..15
    int bn = blockIdx.y;             // 0..55
    int b = bn / NN, n = bn % NN;
    int t4 = threadIdx.x;            // float4 index within row
    int g0 = gs * GCHUNK;
    int g1 = g0 + GCHUNK; if (g1 > GG) g1 = GG;

    const float4* xp = (const float4*)(x + (size_t)(b * TT + n) * DD) + t4;
    float ax = 0.f, ay = 0.f, az = 0.f, aw = 0.f;
    #pragma unroll 4
    for (int g = g0; g < g1; ++g) {
        float4 v = xp[(size_t)g * NN * (DD / 4)];
        ax += v.x; ay += v.y; az += v.z; aw += v.w;
    }
    float4 r; r.x = ax; r.y = ay; r.z = az; r.w = aw;
    ((float4*)partial)[(size_t)(gs * BN + bn) * (DD / 4) + t4] = r;
}

// ---------------------------------------------------------------------------
// K2: reduce partials -> nodes.  grid = 56, block = 256.  [R4 exact]
// ---------------------------------------------------------------------------
__global__ __launch_bounds__(256) void k_mean_reduce(
    const float* __restrict__ partial, float* __restrict__ nodes) {
    int i = blockIdx.x * 256 + threadIdx.x;
    const float4* p = (const float4*)partial;
    float4 a = p[i];
    #pragma unroll
    for (int gs = 1; gs < GSPLIT; ++gs) {
        float4 v = p[(size_t)gs * BN * (DD / 4) + i];
        a.x += v.x; a.y += v.y; a.z += v.z; a.w += v.w;
    }
    const float sc = 1.0f / (float)GG;
    a.x *= sc; a.y *= sc; a.z *= sc; a.w *= sc;
    ((float4*)nodes)[i] = a;
}

// ---------------------------------------------------------------------------
// K3: h = nodes @ W^T.  grid = DD/GD = 256, block 256.  [R4 exact]
// ---------------------------------------------------------------------------
__global__ __launch_bounds__(256) void k_gemv(
    const float* __restrict__ A, const float* __restrict__ Wm,
    float* __restrict__ Cout) {
    int d0 = blockIdx.x * GD;
    int t = threadIdx.x;
    int wave = t >> 6, lane = t & 63;

    float4 wv[GD][4];
    #pragma unroll
    for (int dd = 0; dd < GD; ++dd) {
        const float4* wp = (const float4*)(Wm + (size_t)(d0 + dd) * DD);
        #pragma unroll
        for (int kk = 0; kk < 4; ++kk) wv[dd][kk] = wp[lane + 64 * kk];
    }

    const float4* ap = (const float4*)A + (size_t)(wave * 14) * (DD / 4);
    float acc[14][GD];
    #pragma unroll
    for (int i = 0; i < 14; ++i) {
        const float4* ar = ap + (size_t)i * (DD / 4);
        float4 a0 = ar[lane];
        float4 a1 = ar[lane + 64];
        float4 a2 = ar[lane + 128];
        float4 a3 = ar[lane + 192];
        #pragma unroll
        for (int dd = 0; dd < GD; ++dd) {
            float v = a0.x * wv[dd][0].x + a0.y * wv[dd][0].y +
                      a0.z * wv[dd][0].z + a0.w * wv[dd][0].w;
            v += a1.x * wv[dd][1].x + a1.y * wv[dd][1].y +
                 a1.z * wv[dd][1].z + a1.w * wv[dd][1].w;
            v += a2.x * wv[dd][2].x + a2.y * wv[dd][2].y +
                 a2.z * wv[dd][2].z + a2.w * wv[dd][2].w;
            v += a3.x * wv[dd][3].x + a3.y * wv[dd][3].y +
                 a3.z * wv[dd][3].z + a3.w * wv[dd][3].w;
            acc[i][dd] = v;
        }
    }

    #pragma unroll
    for (int i = 0; i < 14; ++i) {
        #pragma unroll
        for (int dd = 0; dd < GD; ++dd) {
            float v = acc[i][dd];
            v += __shfl_xor(v, 1, 64);
            v += __shfl_xor(v, 2, 64);
            v += __shfl_xor(v, 4, 64);
            v += __shfl_xor(v, 8, 64);
            v += __shfl_xor(v, 16, 64);
            v += __shfl_xor(v, 32, 64);
            if (lane == 0) Cout[(size_t)(wave * 14 + i) * DD + d0 + dd] = v;
        }
    }
}

// ---------------------------------------------------------------------------
// K4: fused attention + gemv2 (the ONE change vs R4).
// grid = DD/GD2 = 512, block 256.
// Prologue: block computes f[2][56] = h @ a1/a2 into LDS.
// Main: wave w owns batches {2w,2w+1}; alpha in registers; A-values formed
// on the fly: s[bn][k] = sum_j alpha_ij h[b][j][k]; dot with out_W columns.
// ---------------------------------------------------------------------------
__global__ __launch_bounds__(256) void k_attn_gemv(
    const float* __restrict__ h, const float* __restrict__ a_w,
    const float* __restrict__ Wm, float* __restrict__ Cout) {
    int d0 = blockIdx.x * GD2;
    int t = threadIdx.x;
    int wave = t >> 6, lane = t & 63;

    __shared__ float f[2][BN];

    for (int task = wave; task < 2 * BN; task += 4) {
        int sel = task & 1;
        int bn = task >> 1;
        const float4* hv4 = (const float4*)(h + (size_t)bn * DD);
        const float4* av4 = (const float4*)(a_w + sel * DD);
        float sum = 0.f;
        #pragma unroll
        for (int c = 0; c < 4; ++c) {
            float4 a = hv4[lane + 64 * c];
            float4 w = av4[lane + 64 * c];
            sum += a.x * w.x + a.y * w.y + a.z * w.z + a.w * w.w;
        }
        sum += __shfl_xor(sum, 1, 64);
        sum += __shfl_xor(sum, 2, 64);
        sum += __shfl_xor(sum, 4, 64);
        sum += __shfl_xor(sum, 8, 64);
        sum += __shfl_xor(sum, 16, 64);
        sum += __shfl_xor(sum, 32, 64);
        if (lane == 0) f[sel][bn] = sum;
    }
    __syncthreads();

    float4 wv[GD2][4];
    #pragma unroll
    for (int dd = 0; dd < GD2; ++dd) {
        const float4* wp = (const float4*)(Wm + (size_t)(d0 + dd) * DD);
        #pragma unroll
        for (int kk = 0; kk < 4; ++kk) wv[dd][kk] = wp[lane + 64 * kk];
    }

    const unsigned msk[NN] = {0x7Eu, 0x45u, 0x0Bu, 0x15u, 0x29u, 0x51u, 0x23u};
    float acc[14][GD2];
    #pragma unroll
    for (int i = 0; i < 14; ++i)
        #pragma unroll
        for (int dd = 0; dd < GD2; ++dd) acc[i][dd] = 0.f;

    #pragma unroll
    for (int bb = 0; bb < 2; ++bb) {
        int b = wave * 2 + bb;

        float alpha[NN][NN];
        #pragma unroll
        for (int i = 0; i < NN; ++i) {
            float f1 = f[0][b * NN + i];
            float m = -1e30f;
            #pragma unroll
            for (int j = 0; j < NN; ++j)
                if ((msk[i] >> j) & 1u) m = fmaxf(m, f1 + f[1][b * NN + j]);
            float ssum = 0.f;
            #pragma unroll
            for (int j = 0; j < NN; ++j) {
                float e = ((msk[i] >> j) & 1u) ? __expf(f1 + f[1][b * NN + j] - m) : 0.f;
                alpha[i][j] = e;
                ssum += e;
            }
            float inv = 1.0f / ssum;
            #pragma unroll
            for (int j = 0; j < NN; ++j) alpha[i][j] *= inv;
        }

        #pragma unroll
        for (int c = 0; c < 4; ++c) {
            float4 h7[NN];
            #pragma unroll
            for (int j = 0; j < NN; ++j)
                h7[j] = ((const float4*)(h + (size_t)(b * NN + j) * DD))[lane + 64 * c];
            #pragma unroll
            for (int i = 0; i < NN; ++i) {
                float ax = 0.f, ay = 0.f, az = 0.f, aw = 0.f;
                #pragma unroll
                for (int j = 0; j < NN; ++j) {
                    float a = alpha[i][j];
                    ax += a * h7[j].x; ay += a * h7[j].y;
                    az += a * h7[j].z; aw += a * h7[j].w;
                }
                #pragma unroll
                for (int dd = 0; dd < GD2; ++dd) {
                    acc[bb * NN + i][dd] += ax * wv[dd][c].x + ay * wv[dd][c].y +
                                            az * wv[dd][c].z + aw * wv[dd][c].w;
                }
            }
        }
    }

    #pragma unroll
    for (int i = 0; i < 14; ++i) {
        #pragma unroll
        for (int dd = 0; dd < GD2; ++dd) {
            float v = acc[i][dd];
            v += __shfl_xor(v, 1, 64);
            v += __shfl_xor(v, 2, 64);
            v += __shfl_xor(v, 4, 64);
            v += __shfl_xor(v, 8, 64);
            v += __shfl_xor(v, 16, 64);
            v += __shfl_xor(v, 32, 64);
            if (lane == 0) Cout[(size_t)(wave * 14 + i) * DD + d0 + dd] = v;
        }
    }
}

// ---------------------------------------------------------------------------
// K5: out[b,t,d] = x[b,t,d] + on[b, t%7, d].  grid = (TT, BB).  [R4 exact]
// ---------------------------------------------------------------------------
__global__ __launch_bounds__(256) void k_final(
    const float* __restrict__ x, const float* __restrict__ on,
    float* __restrict__ out) {
    int t = blockIdx.x;
    int b = blockIdx.y;
    int n = t % NN;
    size_t row4 = (size_t)(b * TT + t) * (DD / 4) + threadIdx.x;
    size_t on4 = (size_t)(b * NN + n) * (DD / 4) + threadIdx.x;
    float4 xv = ((const float4*)x)[row4];
    float4 ov = ((const float4*)on)[on4];
    nfloat4 r;
    r.x = xv.x + ov.x; r.y = xv.y + ov.y;
    r.z = xv.z + ov.z; r.w = xv.w + ov.w;
    __builtin_nontemporal_store(r, (nfloat4*)out + row4);
}

// ---------------------------------------------------------------------------
extern "C" void kernel_launch(void* const* d_in, const int* in_sizes, int n_in,
                              void* d_out, int out_size, void* d_ws, size_t ws_size,
                              hipStream_t stream) {
    const float* x     = (const float*)d_in[0];
    const float* W     = (const float*)d_in[1];
    const float* a_w   = (const float*)d_in[2];
    const float* out_W = (const float*)d_in[3];
    float* out = (float*)d_out;
    float* ws  = (float*)d_ws;

    // ws layout (floats)
    float* partial = ws;                            // 16*56*1024 = 917504
    float* nodes   = ws + 917504;                   // 56*1024
    float* h       = ws + 917504 + 57344;           // 56*1024
    float* on      = ws + 917504 + 2 * 57344;       // 56*1024

    k_mean_partial<<<dim3(GSPLIT, BN), 256, 0, stream>>>(x, partial);
    k_mean_reduce<<<dim3(BN), 256, 0, stream>>>(partial, nodes);
    k_gemv<<<dim3(DD / GD), 256, 0, stream>>>(nodes, W, h);
    k_attn_gemv<<<dim3(DD / GD2), 256, 0, stream>>>(h, a_w, out_W, on);
    k_final<<<dim3(TT, BB), 256, 0, stream>>>(x, on, out);
}

// Round 9
// 117.021 us; speedup vs baseline: 3.9686x; 1.1569x over previous
//
#include <hip/hip_runtime.h>
#include <math.h>

#define BB 8
#define TT 4095
#define DD 1024
#define NN 7
#define GG 585           // TT / NN
#define BN (BB * NN)     // 56
#define GD 4             // gemv: output columns per block

typedef float nfloat4 __attribute__((ext_vector_type(4)));

// ---------------------------------------------------------------------------
// K1: fused group-mean.  grid = (16, BN) — blockIdx.x = 64-float k-slice,
// blockIdx.y = bn.  Thread (gi = t>>4, kg = t&15): sums g = gi, gi+16, ...
// LDS tree-free reduce (16 partials per kg), direct write to nodes.
// No second kernel, no cross-block communication.
// ---------------------------------------------------------------------------
__global__ __launch_bounds__(256) void k_mean(
    const float* __restrict__ x, float* __restrict__ nodes) {
    int ks = blockIdx.x;             // 0..15 (64-float slice of D)
    int bn = blockIdx.y;             // 0..55
    int b = bn / NN, n = bn % NN;
    int t = threadIdx.x;
    int gi = t >> 4;                 // 0..15 g-partition
    int kg = t & 15;                 // 0..15 f4 within slice

    const float4* xp = (const float4*)(x + (size_t)(b * TT + n) * DD) +
                       ks * 16 + kg;
    float ax = 0.f, ay = 0.f, az = 0.f, aw = 0.f;
    for (int g = gi; g < GG; g += 16) {
        float4 v = xp[(size_t)g * NN * (DD / 4)];
        ax += v.x; ay += v.y; az += v.z; aw += v.w;
    }

    __shared__ float4 red[16][16];   // [gi][kg], 4 KB
    float4 r; r.x = ax; r.y = ay; r.z = az; r.w = aw;
    red[gi][kg] = r;
    __syncthreads();

    if (t < 16) {                    // kg = t
        float4 a = red[0][t];
        #pragma unroll
        for (int g2 = 1; g2 < 16; ++g2) {
            float4 v = red[g2][t];
            a.x += v.x; a.y += v.y; a.z += v.z; a.w += v.w;
        }
        const float sc = 1.0f / (float)GG;
        a.x *= sc; a.y *= sc; a.z *= sc; a.w *= sc;
        ((float4*)(nodes + (size_t)bn * DD))[ks * 16 + t] = a;
    }
}

// ---------------------------------------------------------------------------
// K2/K4: C[bn][d] = sum_k A[bn][k] * Wm[d][k]  (A: 56x1024, Wm: 1024x1024)
// grid = DD/GD = 256 blocks, block 256.  [R4 exact]
// ---------------------------------------------------------------------------
__global__ __launch_bounds__(256) void k_gemv(
    const float* __restrict__ A, const float* __restrict__ Wm,
    float* __restrict__ Cout) {
    int d0 = blockIdx.x * GD;
    int t = threadIdx.x;
    int wave = t >> 6, lane = t & 63;

    float4 wv[GD][4];
    #pragma unroll
    for (int dd = 0; dd < GD; ++dd) {
        const float4* wp = (const float4*)(Wm + (size_t)(d0 + dd) * DD);
        #pragma unroll
        for (int kk = 0; kk < 4; ++kk) wv[dd][kk] = wp[lane + 64 * kk];
    }

    const float4* ap = (const float4*)A + (size_t)(wave * 14) * (DD / 4);
    float acc[14][GD];
    #pragma unroll
    for (int i = 0; i < 14; ++i) {
        const float4* ar = ap + (size_t)i * (DD / 4);
        float4 a0 = ar[lane];
        float4 a1 = ar[lane + 64];
        float4 a2 = ar[lane + 128];
        float4 a3 = ar[lane + 192];
        #pragma unroll
        for (int dd = 0; dd < GD; ++dd) {
            float v = a0.x * wv[dd][0].x + a0.y * wv[dd][0].y +
                      a0.z * wv[dd][0].z + a0.w * wv[dd][0].w;
            v += a1.x * wv[dd][1].x + a1.y * wv[dd][1].y +
                 a1.z * wv[dd][1].z + a1.w * wv[dd][1].w;
            v += a2.x * wv[dd][2].x + a2.y * wv[dd][2].y +
                 a2.z * wv[dd][2].z + a2.w * wv[dd][2].w;
            v += a3.x * wv[dd][3].x + a3.y * wv[dd][3].y +
                 a3.z * wv[dd][3].z + a3.w * wv[dd][3].w;
            acc[i][dd] = v;
        }
    }

    #pragma unroll
    for (int i = 0; i < 14; ++i) {
        #pragma unroll
        for (int dd = 0; dd < GD; ++dd) {
            float v = acc[i][dd];
            v += __shfl_xor(v, 1, 64);
            v += __shfl_xor(v, 2, 64);
            v += __shfl_xor(v, 4, 64);
            v += __shfl_xor(v, 8, 64);
            v += __shfl_xor(v, 16, 64);
            v += __shfl_xor(v, 32, 64);
            if (lane == 0) Cout[(size_t)(wave * 14 + i) * DD + d0 + dd] = v;
        }
    }
}

// ---------------------------------------------------------------------------
// K3: per-batch attention.  grid = 8, block = 256.  [R4 exact]
// ---------------------------------------------------------------------------
__global__ __launch_bounds__(256) void k_attn(
    const float* __restrict__ h, const float* __restrict__ a_w,
    float* __restrict__ s) {
    int b = blockIdx.x;
    __shared__ float hl[NN][DD];          // 28 KB
    __shared__ float f[2][NN];
    __shared__ float alpha[NN][NN];

    const float4* hp = (const float4*)(h + (size_t)b * NN * DD);
    float4* hl4 = (float4*)hl;
    for (int i = threadIdx.x; i < NN * (DD / 4); i += 256) hl4[i] = hp[i];
    __syncthreads();

    int wave = threadIdx.x >> 6, lane = threadIdx.x & 63;
    for (int task = wave; task < 2 * NN; task += 4) {
        int n = task % NN, sel = task / NN;
        const float* av = a_w + sel * DD;
        float sum = 0.f;
        for (int k = lane; k < DD; k += 64) sum += hl[n][k] * av[k];
        sum += __shfl_xor(sum, 1, 64);
        sum += __shfl_xor(sum, 2, 64);
        sum += __shfl_xor(sum, 4, 64);
        sum += __shfl_xor(sum, 8, 64);
        sum += __shfl_xor(sum, 16, 64);
        sum += __shfl_xor(sum, 32, 64);
        if (lane == 0) f[sel][n] = sum;
    }
    __syncthreads();

    if (threadIdx.x == 0) {
        const unsigned msk[NN] = {0x7Eu, 0x45u, 0x0Bu, 0x15u, 0x29u, 0x51u, 0x23u};
        #pragma unroll
        for (int i = 0; i < NN; ++i) {
            float m = -1e30f;
            #pragma unroll
            for (int j = 0; j < NN; ++j)
                if ((msk[i] >> j) & 1u) { float e = f[0][i] + f[1][j]; m = fmaxf(m, e); }
            float ssum = 0.f; float ex[NN];
            #pragma unroll
            for (int j = 0; j < NN; ++j) {
                ex[j] = ((msk[i] >> j) & 1u) ? expf(f[0][i] + f[1][j] - m) : 0.f;
                ssum += ex[j];
            }
            float inv = 1.0f / ssum;
            #pragma unroll
            for (int j = 0; j < NN; ++j) alpha[i][j] = ex[j] * inv;
        }
    }
    __syncthreads();

    float4* sp = (float4*)(s + (size_t)b * NN * DD);
    int t = threadIdx.x;
    #pragma unroll
    for (int i = 0; i < NN; ++i) {
        float ax = 0.f, ay = 0.f, az = 0.f, aw = 0.f;
        #pragma unroll
        for (int j = 0; j < NN; ++j) {
            float a = alpha[i][j];
            float4 hv = hl4[j * (DD / 4) + t];
            ax += a * hv.x; ay += a * hv.y; az += a * hv.z; aw += a * hv.w;
        }
        float4 r; r.x = ax; r.y = ay; r.z = az; r.w = aw;
        sp[i * (DD / 4) + t] = r;
    }
}

// ---------------------------------------------------------------------------
// K5: out[b,t,d] = x[b,t,d] + on[b, t%7, d].  grid = (TT, BB).  [R4 exact]
// nt-store keeps out from evicting x in L3 (x 134 MB < 256 MB L3).
// ---------------------------------------------------------------------------
__global__ __launch_bounds__(256) void k_final(
    const float* __restrict__ x, const float* __restrict__ on,
    float* __restrict__ out) {
    int t = blockIdx.x;
    int b = blockIdx.y;
    int n = t % NN;
    size_t row4 = (size_t)(b * TT + t) * (DD / 4) + threadIdx.x;
    size_t on4 = (size_t)(b * NN + n) * (DD / 4) + threadIdx.x;
    float4 xv = ((const float4*)x)[row4];
    float4 ov = ((const float4*)on)[on4];
    nfloat4 r;
    r.x = xv.x + ov.x; r.y = xv.y + ov.y;
    r.z = xv.z + ov.z; r.w = xv.w + ov.w;
    __builtin_nontemporal_store(r, (nfloat4*)out + row4);
}

// ---------------------------------------------------------------------------
extern "C" void kernel_launch(void* const* d_in, const int* in_sizes, int n_in,
                              void* d_out, int out_size, void* d_ws, size_t ws_size,
                              hipStream_t stream) {
    const float* x     = (const float*)d_in[0];
    const float* W     = (const float*)d_in[1];
    const float* a_w   = (const float*)d_in[2];
    const float* out_W = (const float*)d_in[3];
    float* out = (float*)d_out;
    float* ws  = (float*)d_ws;

    // ws layout (floats)
    float* nodes = ws;               // 56*1024
    float* h     = ws + 57344;       // 56*1024
    float* s     = ws + 2 * 57344;   // 56*1024
    float* on    = ws + 3 * 57344;   // 56*1024

    k_mean<<<dim3(16, BN), 256, 0, stream>>>(x, nodes);
    k_gemv<<<dim3(DD / GD), 256, 0, stream>>>(nodes, W, h);
    k_attn<<<dim3(BB), 256, 0, stream>>>(h, a_w, s);
    k_gemv<<<dim3(DD / GD), 256, 0, stream>>>(s, out_W, on);
    k_final<<<dim3(TT, BB), 256, 0, stream>>>(x, on, out);
}

// Round 10
// 108.604 us; speedup vs baseline: 4.2762x; 1.0775x over previous
//
#include <hip/hip_runtime.h>
#include <math.h>

#define BB 8
#define TT 4095
#define DD 1024
#define NN 7
#define GG 585           // TT / NN
#define BN (BB * NN)     // 56
#define GD 4             // gemv1: output columns per block
#define GD2 4            // attn+gemv2: output columns per block
#define NB1 (DD / GD)    // 256 gemv1 blocks (also f-partial count)

typedef float nfloat4 __attribute__((ext_vector_type(4)));

// ---------------------------------------------------------------------------
// K1: fused group-mean.  grid = (16, BN), block = 256.  [R9 + unroll]
// ---------------------------------------------------------------------------
__global__ __launch_bounds__(256) void k_mean(
    const float* __restrict__ x, float* __restrict__ nodes) {
    int ks = blockIdx.x;             // 0..15 (64-float slice of D)
    int bn = blockIdx.y;             // 0..55
    int b = bn / NN, n = bn % NN;
    int t = threadIdx.x;
    int gi = t >> 4;                 // 0..15 g-partition
    int kg = t & 15;                 // 0..15 f4 within slice

    const float4* xp = (const float4*)(x + (size_t)(b * TT + n) * DD) +
                       ks * 16 + kg;
    float ax = 0.f, ay = 0.f, az = 0.f, aw = 0.f;
    #pragma unroll 4
    for (int g = gi; g < GG; g += 16) {
        float4 v = xp[(size_t)g * NN * (DD / 4)];
        ax += v.x; ay += v.y; az += v.z; aw += v.w;
    }

    __shared__ float4 red[16][16];   // [gi][kg], 4 KB
    float4 r; r.x = ax; r.y = ay; r.z = az; r.w = aw;
    red[gi][kg] = r;
    __syncthreads();

    if (t < 16) {                    // kg = t
        float4 a = red[0][t];
        #pragma unroll
        for (int g2 = 1; g2 < 16; ++g2) {
            float4 v = red[g2][t];
            a.x += v.x; a.y += v.y; a.z += v.z; a.w += v.w;
        }
        const float sc = 1.0f / (float)GG;
        a.x *= sc; a.y *= sc; a.z *= sc; a.w *= sc;
        ((float4*)(nodes + (size_t)bn * DD))[ks * 16 + t] = a;
    }
}

// ---------------------------------------------------------------------------
// K2: h = nodes @ W^T  +  per-block f-partials.
// grid = NB1 = 256, block 256.  Wave w owns rows [14w,14w+14).
// After the butterfly every lane holds h[r][d]; we fold the f1/f2 partial
// (h[r][d]*a_w[d], d in this block's 4 columns) at negligible cost.
// fpart layout: [sel][blk][row], sel-stride NB1*BN.
// ---------------------------------------------------------------------------
__global__ __launch_bounds__(256) void k_gemv_f(
    const float* __restrict__ A, const float* __restrict__ Wm,
    const float* __restrict__ a_w,
    float* __restrict__ Cout, float* __restrict__ fpart) {
    int d0 = blockIdx.x * GD;
    int t = threadIdx.x;
    int wave = t >> 6, lane = t & 63;

    float4 wv[GD][4];
    #pragma unroll
    for (int dd = 0; dd < GD; ++dd) {
        const float4* wp = (const float4*)(Wm + (size_t)(d0 + dd) * DD);
        #pragma unroll
        for (int kk = 0; kk < 4; ++kk) wv[dd][kk] = wp[lane + 64 * kk];
    }

    const float4* ap = (const float4*)A + (size_t)(wave * 14) * (DD / 4);
    float acc[14][GD];
    #pragma unroll
    for (int i = 0; i < 14; ++i) {
        const float4* ar = ap + (size_t)i * (DD / 4);
        float4 a0 = ar[lane];
        float4 a1 = ar[lane + 64];
        float4 a2 = ar[lane + 128];
        float4 a3 = ar[lane + 192];
        #pragma unroll
        for (int dd = 0; dd < GD; ++dd) {
            float v = a0.x * wv[dd][0].x + a0.y * wv[dd][0].y +
                      a0.z * wv[dd][0].z + a0.w * wv[dd][0].w;
            v += a1.x * wv[dd][1].x + a1.y * wv[dd][1].y +
                 a1.z * wv[dd][1].z + a1.w * wv[dd][1].w;
            v += a2.x * wv[dd][2].x + a2.y * wv[dd][2].y +
                 a2.z * wv[dd][2].z + a2.w * wv[dd][2].w;
            v += a3.x * wv[dd][3].x + a3.y * wv[dd][3].y +
                 a3.z * wv[dd][3].z + a3.w * wv[dd][3].w;
            acc[i][dd] = v;
        }
    }

    float a1v[GD], a2v[GD];
    #pragma unroll
    for (int dd = 0; dd < GD; ++dd) {
        a1v[dd] = a_w[d0 + dd];
        a2v[dd] = a_w[DD + d0 + dd];
    }

    #pragma unroll
    for (int i = 0; i < 14; ++i) {
        float f1i = 0.f, f2i = 0.f;
        #pragma unroll
        for (int dd = 0; dd < GD; ++dd) {
            float v = acc[i][dd];
            v += __shfl_xor(v, 1, 64);
            v += __shfl_xor(v, 2, 64);
            v += __shfl_xor(v, 4, 64);
            v += __shfl_xor(v, 8, 64);
            v += __shfl_xor(v, 16, 64);
            v += __shfl_xor(v, 32, 64);
            f1i += v * a1v[dd];
            f2i += v * a2v[dd];
            if (lane == 0) Cout[(size_t)(wave * 14 + i) * DD + d0 + dd] = v;
        }
        if (lane == 0) {
            int row = wave * 14 + i;
            fpart[(size_t)blockIdx.x * BN + row] = f1i;
            fpart[(size_t)(NB1 + blockIdx.x) * BN + row] = f2i;
        }
    }
}

// ---------------------------------------------------------------------------
// K3: fused attention + gemv2.  grid = DD/GD2 = 256, block 256.
// Prologue: reduce fpart -> f[2][56] in LDS (cheap, coalesced).
// Wave w owns batches {2w,2w+1}: alpha in registers (from f), PV formed on
// the fly from h, dotted with out_W columns d0..d0+3.
// ---------------------------------------------------------------------------
__global__ __launch_bounds__(256) void k_attn_gemv(
    const float* __restrict__ h, const float* __restrict__ fpart,
    const float* __restrict__ Wm, float* __restrict__ Cout) {
    int d0 = blockIdx.x * GD2;
    int t = threadIdx.x;
    int wave = t >> 6, lane = t & 63;

    __shared__ float f[2][BN];

    if (t < 2 * BN) {
        int sel = t / BN, row = t - sel * BN;
        const float* fp = fpart + (size_t)sel * NB1 * BN + row;
        float s0 = 0.f, s1 = 0.f, s2 = 0.f, s3 = 0.f;
        #pragma unroll 4
        for (int blk = 0; blk < NB1; blk += 4) {
            s0 += fp[(size_t)blk * BN];
            s1 += fp[(size_t)(blk + 1) * BN];
            s2 += fp[(size_t)(blk + 2) * BN];
            s3 += fp[(size_t)(blk + 3) * BN];
        }
        f[sel][row] = (s0 + s1) + (s2 + s3);
    }
    __syncthreads();

    const unsigned msk[NN] = {0x7Eu, 0x45u, 0x0Bu, 0x15u, 0x29u, 0x51u, 0x23u};
    float acc[14][GD2];
    #pragma unroll
    for (int i = 0; i < 14; ++i)
        #pragma unroll
        for (int dd = 0; dd < GD2; ++dd) acc[i][dd] = 0.f;

    #pragma unroll
    for (int bb = 0; bb < 2; ++bb) {
        int b = wave * 2 + bb;

        float alpha[NN][NN];
        #pragma unroll
        for (int i = 0; i < NN; ++i) {
            float f1 = f[0][b * NN + i];
            float m = -1e30f;
            #pragma unroll
            for (int j = 0; j < NN; ++j)
                if ((msk[i] >> j) & 1u) m = fmaxf(m, f1 + f[1][b * NN + j]);
            float ssum = 0.f;
            #pragma unroll
            for (int j = 0; j < NN; ++j) {
                float e = ((msk[i] >> j) & 1u) ? __expf(f1 + f[1][b * NN + j] - m) : 0.f;
                alpha[i][j] = e;
                ssum += e;
            }
            float inv = 1.0f / ssum;
            #pragma unroll
            for (int j = 0; j < NN; ++j) alpha[i][j] *= inv;
        }

        #pragma unroll
        for (int c = 0; c < 4; ++c) {
            float4 wvc[GD2];
            #pragma unroll
            for (int dd = 0; dd < GD2; ++dd)
                wvc[dd] = ((const float4*)(Wm + (size_t)(d0 + dd) * DD))[lane + 64 * c];
            float4 h7[NN];
            #pragma unroll
            for (int j = 0; j < NN; ++j)
                h7[j] = ((const float4*)(h + (size_t)(b * NN + j) * DD))[lane + 64 * c];
            #pragma unroll
            for (int i = 0; i < NN; ++i) {
                float ax = 0.f, ay = 0.f, az = 0.f, aw = 0.f;
                #pragma unroll
                for (int j = 0; j < NN; ++j) {
                    float a = alpha[i][j];
                    ax += a * h7[j].x; ay += a * h7[j].y;
                    az += a * h7[j].z; aw += a * h7[j].w;
                }
                #pragma unroll
                for (int dd = 0; dd < GD2; ++dd) {
                    acc[bb * NN + i][dd] += ax * wvc[dd].x + ay * wvc[dd].y +
                                            az * wvc[dd].z + aw * wvc[dd].w;
                }
            }
        }
    }

    #pragma unroll
    for (int bb = 0; bb < 2; ++bb) {
        #pragma unroll
        for (int i = 0; i < NN; ++i) {
            #pragma unroll
            for (int dd = 0; dd < GD2; ++dd) {
                float v = acc[bb * NN + i][dd];
                v += __shfl_xor(v, 1, 64);
                v += __shfl_xor(v, 2, 64);
                v += __shfl_xor(v, 4, 64);
                v += __shfl_xor(v, 8, 64);
                v += __shfl_xor(v, 16, 64);
                v += __shfl_xor(v, 32, 64);
                if (lane == 0)
                    Cout[(size_t)((wave * 2 + bb) * NN + i) * DD + d0 + dd] = v;
            }
        }
    }
}

// ---------------------------------------------------------------------------
// K4: out[b,t,d] = x[b,t,d] + on[b, t%7, d].  grid = (TT, BB).  [R9 exact]
// ---------------------------------------------------------------------------
__global__ __launch_bounds__(256) void k_final(
    const float* __restrict__ x, const float* __restrict__ on,
    float* __restrict__ out) {
    int t = blockIdx.x;
    int b = blockIdx.y;
    int n = t % NN;
    size_t row4 = (size_t)(b * TT + t) * (DD / 4) + threadIdx.x;
    size_t on4 = (size_t)(b * NN + n) * (DD / 4) + threadIdx.x;
    float4 xv = ((const float4*)x)[row4];
    float4 ov = ((const float4*)on)[on4];
    nfloat4 r;
    r.x = xv.x + ov.x; r.y = xv.y + ov.y;
    r.z = xv.z + ov.z; r.w = xv.w + ov.w;
    __builtin_nontemporal_store(r, (nfloat4*)out + row4);
}

// ---------------------------------------------------------------------------
extern "C" void kernel_launch(void* const* d_in, const int* in_sizes, int n_in,
                              void* d_out, int out_size, void* d_ws, size_t ws_size,
                              hipStream_t stream) {
    const float* x     = (const float*)d_in[0];
    const float* W     = (const float*)d_in[1];
    const float* a_w   = (const float*)d_in[2];
    const float* out_W = (const float*)d_in[3];
    float* out = (float*)d_out;
    float* ws  = (float*)d_ws;

    // ws layout (floats)
    float* nodes = ws;                       // 56*1024
    float* h     = ws + 57344;               // 56*1024
    float* on    = ws + 2 * 57344;           // 56*1024
    float* fpart = ws + 3 * 57344;           // 2*256*56 = 28672

    k_mean<<<dim3(16, BN), 256, 0, stream>>>(x, nodes);
    k_gemv_f<<<dim3(NB1), 256, 0, stream>>>(nodes, W, a_w, h, fpart);
    k_attn_gemv<<<dim3(DD / GD2), 256, 0, stream>>>(h, fpart, out_W, on);
    k_final<<<dim3(TT, BB), 256, 0, stream>>>(x, on, out);
}

// Round 11
// 93.750 us; speedup vs baseline: 4.9536x; 1.1584x over previous
//
#include <hip/hip_runtime.h>
#include <math.h>

#define BB 8
#define TT 4095
#define DD 1024
#define NN 7
#define GG 585           // TT / NN
#define BN (BB * NN)     // 56
#define GD 4             // gemv1: output columns per block
#define GD2 4            // attn+gemv2: output columns per block
#define NB1 (DD / GD)    // 256 gemv1 blocks (also f-partial count)
#define KS 32            // k_mean: number of k-slices (8 float4 each)

typedef float nfloat4 __attribute__((ext_vector_type(4)));

// ---------------------------------------------------------------------------
// K1: fused group-mean.  grid = (KS=32, BN) = 1792 blocks (7.0/CU), block 256.
// Thread (gi = t>>3 in [0,32), kg = t&7): sums g = gi, gi+32, ...
// ---------------------------------------------------------------------------
__global__ __launch_bounds__(256) void k_mean(
    const float* __restrict__ x, float* __restrict__ nodes) {
    int ks = blockIdx.x;             // 0..31 (8-float4 slice of D)
    int bn = blockIdx.y;             // 0..55
    int b = bn / NN, n = bn % NN;
    int t = threadIdx.x;
    int gi = t >> 3;                 // 0..31 g-partition
    int kg = t & 7;                  // 0..7 f4 within slice

    const float4* xp = (const float4*)(x + (size_t)(b * TT + n) * DD) +
                       ks * 8 + kg;
    float ax = 0.f, ay = 0.f, az = 0.f, aw = 0.f;
    #pragma unroll 4
    for (int g = gi; g < GG; g += 32) {
        float4 v = xp[(size_t)g * NN * (DD / 4)];
        ax += v.x; ay += v.y; az += v.z; aw += v.w;
    }

    __shared__ float4 red[32][8];    // [gi][kg], 4 KB
    float4 r; r.x = ax; r.y = ay; r.z = az; r.w = aw;
    red[gi][kg] = r;
    __syncthreads();

    if (t < 8) {                     // kg = t
        float4 a = red[0][t];
        #pragma unroll
        for (int g2 = 1; g2 < 32; ++g2) {
            float4 v = red[g2][t];
            a.x += v.x; a.y += v.y; a.z += v.z; a.w += v.w;
        }
        const float sc = 1.0f / (float)GG;
        a.x *= sc; a.y *= sc; a.z *= sc; a.w *= sc;
        ((float4*)(nodes + (size_t)bn * DD))[ks * 8 + t] = a;
    }
}

// ---------------------------------------------------------------------------
// K2: h = nodes @ W^T + per-block f-partials.  grid = NB1, block = 512
// (8 waves, 2/SIMD for latency hiding).  Wave w owns rows [7w, 7w+7).
// ---------------------------------------------------------------------------
__global__ __launch_bounds__(512) void k_gemv_f(
    const float* __restrict__ A, const float* __restrict__ Wm,
    const float* __restrict__ a_w,
    float* __restrict__ Cout, float* __restrict__ fpart) {
    int d0 = blockIdx.x * GD;
    int t = threadIdx.x;
    int wave = t >> 6, lane = t & 63;

    float4 wv[GD][4];
    #pragma unroll
    for (int dd = 0; dd < GD; ++dd) {
        const float4* wp = (const float4*)(Wm + (size_t)(d0 + dd) * DD);
        #pragma unroll
        for (int kk = 0; kk < 4; ++kk) wv[dd][kk] = wp[lane + 64 * kk];
    }

    const float4* ap = (const float4*)A + (size_t)(wave * 7) * (DD / 4);
    float acc[7][GD];
    #pragma unroll
    for (int i = 0; i < 7; ++i) {
        const float4* ar = ap + (size_t)i * (DD / 4);
        float4 a0 = ar[lane];
        float4 a1 = ar[lane + 64];
        float4 a2 = ar[lane + 128];
        float4 a3 = ar[lane + 192];
        #pragma unroll
        for (int dd = 0; dd < GD; ++dd) {
            float v = a0.x * wv[dd][0].x + a0.y * wv[dd][0].y +
                      a0.z * wv[dd][0].z + a0.w * wv[dd][0].w;
            v += a1.x * wv[dd][1].x + a1.y * wv[dd][1].y +
                 a1.z * wv[dd][1].z + a1.w * wv[dd][1].w;
            v += a2.x * wv[dd][2].x + a2.y * wv[dd][2].y +
                 a2.z * wv[dd][2].z + a2.w * wv[dd][2].w;
            v += a3.x * wv[dd][3].x + a3.y * wv[dd][3].y +
                 a3.z * wv[dd][3].z + a3.w * wv[dd][3].w;
            acc[i][dd] = v;
        }
    }

    float a1v[GD], a2v[GD];
    #pragma unroll
    for (int dd = 0; dd < GD; ++dd) {
        a1v[dd] = a_w[d0 + dd];
        a2v[dd] = a_w[DD + d0 + dd];
    }

    #pragma unroll
    for (int i = 0; i < 7; ++i) {
        float f1i = 0.f, f2i = 0.f;
        #pragma unroll
        for (int dd = 0; dd < GD; ++dd) {
            float v = acc[i][dd];
            v += __shfl_xor(v, 1, 64);
            v += __shfl_xor(v, 2, 64);
            v += __shfl_xor(v, 4, 64);
            v += __shfl_xor(v, 8, 64);
            v += __shfl_xor(v, 16, 64);
            v += __shfl_xor(v, 32, 64);
            f1i += v * a1v[dd];
            f2i += v * a2v[dd];
            if (lane == 0) Cout[(size_t)(wave * 7 + i) * DD + d0 + dd] = v;
        }
        if (lane == 0) {
            int row = wave * 7 + i;
            fpart[(size_t)blockIdx.x * BN + row] = f1i;
            fpart[(size_t)(NB1 + blockIdx.x) * BN + row] = f2i;
        }
    }
}

// ---------------------------------------------------------------------------
// K3: fused attention + gemv2.  grid = DD/GD2 = 256, block = 512 (8 waves).
// Prologue: reduce fpart -> f[2][56] in LDS.  Wave w owns batch w.
// ---------------------------------------------------------------------------
__global__ __launch_bounds__(512) void k_attn_gemv(
    const float* __restrict__ h, const float* __restrict__ fpart,
    const float* __restrict__ Wm, float* __restrict__ Cout) {
    int d0 = blockIdx.x * GD2;
    int t = threadIdx.x;
    int wave = t >> 6, lane = t & 63;

    __shared__ float f[2][BN];

    if (t < 2 * BN) {
        int sel = t / BN, row = t - sel * BN;
        const float* fp = fpart + (size_t)sel * NB1 * BN + row;
        float s0 = 0.f, s1 = 0.f, s2 = 0.f, s3 = 0.f;
        #pragma unroll 4
        for (int blk = 0; blk < NB1; blk += 4) {
            s0 += fp[(size_t)blk * BN];
            s1 += fp[(size_t)(blk + 1) * BN];
            s2 += fp[(size_t)(blk + 2) * BN];
            s3 += fp[(size_t)(blk + 3) * BN];
        }
        f[sel][row] = (s0 + s1) + (s2 + s3);
    }
    __syncthreads();

    const unsigned msk[NN] = {0x7Eu, 0x45u, 0x0Bu, 0x15u, 0x29u, 0x51u, 0x23u};
    int b = wave;                    // one batch per wave

    float alpha[NN][NN];
    #pragma unroll
    for (int i = 0; i < NN; ++i) {
        float f1 = f[0][b * NN + i];
        float m = -1e30f;
        #pragma unroll
        for (int j = 0; j < NN; ++j)
            if ((msk[i] >> j) & 1u) m = fmaxf(m, f1 + f[1][b * NN + j]);
        float ssum = 0.f;
        #pragma unroll
        for (int j = 0; j < NN; ++j) {
            float e = ((msk[i] >> j) & 1u) ? __expf(f1 + f[1][b * NN + j] - m) : 0.f;
            alpha[i][j] = e;
            ssum += e;
        }
        float inv = 1.0f / ssum;
        #pragma unroll
        for (int j = 0; j < NN; ++j) alpha[i][j] *= inv;
    }

    float acc[NN][GD2];
    #pragma unroll
    for (int i = 0; i < NN; ++i)
        #pragma unroll
        for (int dd = 0; dd < GD2; ++dd) acc[i][dd] = 0.f;

    #pragma unroll
    for (int c = 0; c < 4; ++c) {
        float4 wvc[GD2];
        #pragma unroll
        for (int dd = 0; dd < GD2; ++dd)
            wvc[dd] = ((const float4*)(Wm + (size_t)(d0 + dd) * DD))[lane + 64 * c];
        float4 h7[NN];
        #pragma unroll
        for (int j = 0; j < NN; ++j)
            h7[j] = ((const float4*)(h + (size_t)(b * NN + j) * DD))[lane + 64 * c];
        #pragma unroll
        for (int i = 0; i < NN; ++i) {
            float ax = 0.f, ay = 0.f, az = 0.f, aw = 0.f;
            #pragma unroll
            for (int j = 0; j < NN; ++j) {
                float a = alpha[i][j];
                ax += a * h7[j].x; ay += a * h7[j].y;
                az += a * h7[j].z; aw += a * h7[j].w;
            }
            #pragma unroll
            for (int dd = 0; dd < GD2; ++dd) {
                acc[i][dd] += ax * wvc[dd].x + ay * wvc[dd].y +
                              az * wvc[dd].z + aw * wvc[dd].w;
            }
        }
    }

    #pragma unroll
    for (int i = 0; i < NN; ++i) {
        #pragma unroll
        for (int dd = 0; dd < GD2; ++dd) {
            float v = acc[i][dd];
            v += __shfl_xor(v, 1, 64);
            v += __shfl_xor(v, 2, 64);
            v += __shfl_xor(v, 4, 64);
            v += __shfl_xor(v, 8, 64);
            v += __shfl_xor(v, 16, 64);
            v += __shfl_xor(v, 32, 64);
            if (lane == 0)
                Cout[(size_t)(b * NN + i) * DD + d0 + dd] = v;
        }
    }
}

// ---------------------------------------------------------------------------
// K4: out[b,t,d] = x[b,t,d] + on[b, t%7, d].  grid = (TT, BB).  [R10 exact]
// ---------------------------------------------------------------------------
__global__ __launch_bounds__(256) void k_final(
    const float* __restrict__ x, const float* __restrict__ on,
    float* __restrict__ out) {
    int t = blockIdx.x;
    int b = blockIdx.y;
    int n = t % NN;
    size_t row4 = (size_t)(b * TT + t) * (DD / 4) + threadIdx.x;
    size_t on4 = (size_t)(b * NN + n) * (DD / 4) + threadIdx.x;
    float4 xv = ((const float4*)x)[row4];
    float4 ov = ((const float4*)on)[on4];
    nfloat4 r;
    r.x = xv.x + ov.x; r.y = xv.y + ov.y;
    r.z = xv.z + ov.z; r.w = xv.w + ov.w;
    __builtin_nontemporal_store(r, (nfloat4*)out + row4);
}

// ---------------------------------------------------------------------------
extern "C" void kernel_launch(void* const* d_in, const int* in_sizes, int n_in,
                              void* d_out, int out_size, void* d_ws, size_t ws_size,
                              hipStream_t stream) {
    const float* x     = (const float*)d_in[0];
    const float* W     = (const float*)d_in[1];
    const float* a_w   = (const float*)d_in[2];
    const float* out_W = (const float*)d_in[3];
    float* out = (float*)d_out;
    float* ws  = (float*)d_ws;

    // ws layout (floats)
    float* nodes = ws;                       // 56*1024
    float* h     = ws + 57344;               // 56*1024
    float* on    = ws + 2 * 57344;           // 56*1024
    float* fpart = ws + 3 * 57344;           // 2*256*56 = 28672

    k_mean<<<dim3(KS, BN), 256, 0, stream>>>(x, nodes);
    k_gemv_f<<<dim3(NB1), 512, 0, stream>>>(nodes, W, a_w, h, fpart);
    k_attn_gemv<<<dim3(DD / GD2), 512, 0, stream>>>(h, fpart, out_W, on);
    k_final<<<dim3(TT, BB), 256, 0, stream>>>(x, on, out);
}